// Round 3
// baseline (2086.891 us; speedup 1.0000x reference)
//
#include <hip/hip_runtime.h>
#include <hip/hip_cooperative_groups.h>

namespace cg = cooperative_groups;

#define DIM   256
#define BATCH 16
#define STEPS 32
#define TS    32
#define PAD   3
#define HS    (TS + 2*PAD)   // 38

// Collapse the 14 used fd_kernels into one effective 7x7 kernel.
// eff[t] = sum_{c=1..14} fdk[c,0,t] * cw[c-1]   (kernel 0 unused: u1fd[:,1:])
__global__ void prep_eff(const float* __restrict__ fdk,
                         const float* __restrict__ cw,
                         float* __restrict__ eff) {
    int t = threadIdx.x;
    if (t < 49) {
        float s = 0.f;
        #pragma unroll
        for (int c = 1; c < 15; ++c)
            s += fdk[c * 49 + t] * cw[c - 1];
        eff[t] = s;
    }
}

// ---------------- fallback path (round-1, known good, 353 us) ----------------
__global__ __launch_bounds__(256) void step_kernel(
    const float* __restrict__ u1c, const float* __restrict__ u0c,
    const float* __restrict__ epsr, const float* __restrict__ sigma,
    const float* __restrict__ eff, const float* __restrict__ src,
    float* __restrict__ u2, int s)
{
    __shared__ float tile[14][HS];
    const int t  = threadIdx.x;
    const int x0 = blockIdx.x * 32;
    const int y0 = blockIdx.y * 8;
    const int b  = blockIdx.z;
    const float* u1b = u1c + (size_t)b * DIM * DIM;

    for (int i = t; i < HS * 14; i += 256) {
        int hy = i / HS, hx = i - hy * HS;
        int gy = y0 + hy - PAD, gx = x0 + hx - PAD;
        float v = 0.f;
        if (gy >= 0 && gy < DIM && gx >= 0 && gx < DIM) v = u1b[gy * DIM + gx];
        tile[hy][hx] = v;
    }
    __syncthreads();

    const int lx = t & 31, ly = t >> 5;
    const int gx = x0 + lx, gy = y0 + ly;
    float combo = 0.f;
    #pragma unroll
    for (int kh = 0; kh < 7; ++kh)
        #pragma unroll
        for (int kw = 0; kw < 7; ++kw)
            combo = fmaf(tile[ly + kh][lx + kw], eff[kh * 7 + kw], combo);

    const size_t idx = (size_t)b * DIM * DIM + (size_t)gy * DIM + gx;
    const float e = epsr[idx], sg = sigma[idx];
    const float u1v = tile[ly + PAD][lx + PAD];
    float rhs = combo + 8.f * e * u1v - (4.f * e - sg) * u0c[idx];
    if (gy == 128 && gx == 128) rhs += -(src[2 * s] - src[2 * s + 1]);
    u2[idx] = rhs / (4.f * e + sg);
}

// ---------------- persistent cooperative path ----------------
// 512 blocks (need 2/CU; launch_bounds(256,4) caps VGPR<=128 -> capacity >=4/CU
// => 2x margin on the cooperative co-residency check that killed round 2).
// Each block: one 32x32 tile, TWO batches phased through one LDS tile.
__global__ __launch_bounds__(256, 4) void fdtd_coop(
    const float* __restrict__ u1_in, const float* __restrict__ u0_in,
    const float* __restrict__ epsr,  const float* __restrict__ sigma,
    const float* __restrict__ eff,   const float* __restrict__ src,
    float* __restrict__ exA, float* __restrict__ exB,
    float* __restrict__ out)
{
    __shared__ float T[HS][HS];   // stride 38 floats: 2-way bank alias only -> free
    cg::grid_group grid = cg::this_grid();

    const int t  = threadIdx.x;
    const int lx = t & 31;
    const int r0 = (t >> 5) * 4;          // 4 owned rows per thread
    const int blk  = blockIdx.x;          // 0..511
    const int tile = blk & 63;
    const int x0 = (tile & 7) * TS;
    const int y0 = (tile >> 3) * TS;
    const int b0 = (blk >> 6) * 2;        // this block's two batches
    const size_t bofs0 = (size_t)b0 * DIM * DIM;
    const size_t bofs1 = bofs0 + (size_t)DIM * DIM;
    const int gx = x0 + lx;

    // persistent per-pixel state (registers for all 32 steps)
    float u0v[2][4], u1v[2][4], Pc[2][4], Ac[2][4], Bc[2][4];
    #pragma unroll
    for (int q = 0; q < 2; ++q) {
        const size_t bo = q ? bofs1 : bofs0;
        #pragma unroll
        for (int k = 0; k < 4; ++k) {
            const size_t idx = bo + (size_t)(y0 + r0 + k) * DIM + gx;
            u1v[q][k] = u1_in[idx];
            u0v[q][k] = u0_in[idx];
            const float e = epsr[idx], sg = sigma[idx];
            const float pp = 1.f / (4.f * e + sg);   // exact div once, reused 32x
            Pc[q][k] = pp;
            Ac[q][k] = 8.f * e * pp;
            Bc[q][k] = (4.f * e - sg) * pp;
        }
    }

    #pragma unroll 1
    for (int s = 0; s < STEPS; ++s) {
        float acc[2][4];
        const float* ub = (s == 0) ? u1_in : ((s & 1) ? exA : exB);

        #pragma unroll
        for (int q = 0; q < 2; ++q) {
            const size_t bo = q ? bofs1 : bofs0;
            // own u1 -> LDS center
            #pragma unroll
            for (int k = 0; k < 4; ++k)
                T[PAD + r0 + k][PAD + lx] = u1v[q][k];
            // halo ring (420 px) from neighbors' published borders
            for (int i = t; i < 420; i += 256) {
                int hy, hx;
                if (i < 114)      { hy = i / HS;                       hx = i % HS; }
                else if (i < 228) { int j = i - 114; hy = 35 + j / HS; hx = j % HS; }
                else if (i < 324) { int j = i - 228; hy = PAD + j / 3; hx = j % 3; }
                else              { int j = i - 324; hy = PAD + j / 3; hx = 35 + j % 3; }
                const int gyy = y0 + hy - PAD, gxx = x0 + hx - PAD;
                float v = 0.f;
                if (gyy >= 0 && gyy < DIM && gxx >= 0 && gxx < DIM)
                    v = ub[bo + (size_t)gyy * DIM + gxx];
                T[hy][hx] = v;
            }
            __syncthreads();

            // 7x7 conv with vertical row reuse: 70 LDS row-reads per 4 outputs
            float a0 = 0.f, a1 = 0.f, a2 = 0.f, a3 = 0.f;
            #pragma unroll
            for (int ky = 0; ky < 10; ++ky) {
                float v[7];
                #pragma unroll
                for (int kw = 0; kw < 7; ++kw) v[kw] = T[r0 + ky][lx + kw];
                if (ky < 7) {
                    #pragma unroll
                    for (int kw = 0; kw < 7; ++kw) a0 = fmaf(v[kw], eff[ky * 7 + kw], a0);
                }
                if (ky >= 1 && ky < 8) {
                    #pragma unroll
                    for (int kw = 0; kw < 7; ++kw) a1 = fmaf(v[kw], eff[(ky - 1) * 7 + kw], a1);
                }
                if (ky >= 2 && ky < 9) {
                    #pragma unroll
                    for (int kw = 0; kw < 7; ++kw) a2 = fmaf(v[kw], eff[(ky - 2) * 7 + kw], a2);
                }
                if (ky >= 3) {
                    #pragma unroll
                    for (int kw = 0; kw < 7; ++kw) a3 = fmaf(v[kw], eff[(ky - 3) * 7 + kw], a3);
                }
            }
            acc[q][0] = a0; acc[q][1] = a1; acc[q][2] = a2; acc[q][3] = a3;
            __syncthreads();   // T reused by next phase / next step
        }

        // pointwise update + source injection
        #pragma unroll
        for (int q = 0; q < 2; ++q)
            #pragma unroll
            for (int k = 0; k < 4; ++k) {
                float u2 = fmaf(Pc[q][k], acc[q][k],
                            fmaf(Ac[q][k], u1v[q][k], -(Bc[q][k] * u0v[q][k])));
                u0v[q][k] = u1v[q][k];
                u1v[q][k] = u2;
            }
        if (gx == 128 && y0 == 128 && r0 == 0) {
            const float ds = src[2 * s] - src[2 * s + 1];
            #pragma unroll
            for (int q = 0; q < 2; ++q)
                u1v[q][0] = fmaf(-Pc[q][0], ds, u1v[q][0]);   // row 128 = y0+r0+0
        }

        if (s == STEPS - 1) {
            #pragma unroll
            for (int q = 0; q < 2; ++q) {
                const size_t bo = q ? bofs1 : bofs0;
                #pragma unroll
                for (int k = 0; k < 4; ++k)
                    out[bo + (size_t)(y0 + r0 + k) * DIM + gx] = u1v[q][k];
            }
        } else {
            float* exW = (s & 1) ? exB : exA;
            #pragma unroll
            for (int q = 0; q < 2; ++q) {
                const size_t bo = q ? bofs1 : bofs0;
                #pragma unroll
                for (int k = 0; k < 4; ++k) {
                    const int r = r0 + k;
                    if (lx < 3 || lx > 28 || r < 3 || r > 28)   // 3-wide border only
                        exW[bo + (size_t)(y0 + r) * DIM + gx] = u1v[q][k];
                }
            }
            grid.sync();   // all step-s borders visible before step s+1 reads
        }
    }
}

extern "C" void kernel_launch(void* const* d_in, const int* in_sizes, int n_in,
                              void* d_out, int out_size, void* d_ws, size_t ws_size,
                              hipStream_t stream) {
    (void)in_sizes; (void)n_in; (void)out_size; (void)ws_size;

    const float* u1    = (const float*)d_in[0];
    const float* u0    = (const float*)d_in[1];
    const float* epsr  = (const float*)d_in[2];
    const float* sigma = (const float*)d_in[3];
    const float* fdk   = (const float*)d_in[4];
    const float* cw    = (const float*)d_in[5];
    const float* src   = (const float*)d_in[6];

    float* eff = (float*)d_ws;
    float* exA = (float*)((char*)d_ws + 256);
    float* exB = exA + (size_t)BATCH * DIM * DIM;
    float* out = (float*)d_out;

    prep_eff<<<1, 64, 0, stream>>>(fdk, cw, eff);

    // capture-safe, deterministic capability check (same result every call)
    int nb = 0;
    hipError_t qe = hipOccupancyMaxActiveBlocksPerMultiprocessor(&nb, fdtd_coop, 256, 0);
    bool coop = (qe == hipSuccess) && (nb >= 2);   // need 512 blocks on 256 CUs

    if (coop) {
        const float* effc = eff;
        void* args[] = { (void*)&u1, (void*)&u0, (void*)&epsr, (void*)&sigma,
                         (void*)&effc, (void*)&src, (void*)&exA, (void*)&exB,
                         (void*)&out };
        hipError_t le = hipLaunchCooperativeKernel((void*)fdtd_coop,
                                                   dim3(512), dim3(256),
                                                   args, 0, stream);
        if (le == hipSuccess) return;
    }

    // fallback: known-good multi-launch chain (uses exA/exB as ping-pong)
    dim3 grid(DIM / 32, DIM / 8, BATCH);
    const float* pu0 = u0;
    const float* pu1 = u1;
    for (int s = 0; s < STEPS; ++s) {
        float* o;
        if (s == STEPS - 1)      o = out;
        else if (s == 0)         o = exA;
        else if (s == 1)         o = exB;
        else                     o = (float*)pu0;  // in-place over retiring ws buffer
        step_kernel<<<grid, 256, 0, stream>>>(pu1, pu0, epsr, sigma, eff, src, o, s);
        pu0 = pu1;
        pu1 = o;
    }
}

// Round 4
// 325.826 us; speedup vs baseline: 6.4049x; 6.4049x over previous
//
#include <hip/hip_runtime.h>

#define DIM   256
#define BATCH 16
#define STEPS 32

// Fused-4 geometry: TS=64 output tile, halo 12, LDS region 88x88.
// Sub-step r (r=0..3) computes u_{s+r+1} on region [OFF, OFF+N) with
// OFF = 3*(r+1), N = 88 - 6*(r+1):  (82,3) (76,6) (70,9) (64,12).

// Collapse the 14 used fd_kernels into one effective 7x7 kernel.
// eff[t] = sum_{c=1..14} fdk[c,0,t] * cw[c-1]   (kernel 0 unused: u1fd[:,1:])
__global__ void prep_eff(const float* __restrict__ fdk,
                         const float* __restrict__ cw,
                         float* __restrict__ eff) {
    int t = threadIdx.x;
    if (t < 49) {
        float s = 0.f;
        #pragma unroll
        for (int c = 1; c < 15; ++c)
            s += fdk[c * 49 + t] * cw[c - 1];
        eff[t] = s;
    }
}

// One fused sub-step over LDS.
//   out = D1*conv7x7(Fs) + u1 + G*(u1 - u0),  u1 = Fs[center], u0 = Fd[center]
// (algebraically identical to reference: D1=1/(4e+sg), G=(4e-sg)*D1, 8e*D1=1+G)
// Result overwrites Fd in place (each pixel has a single owner thread).
// Pixels outside the image come out exactly 0 because D1=G=0 and field=0 there.
template<int N, int OFF>
__device__ __forceinline__ void substep(
    const float (*__restrict__ Fs)[88],  // conv + u1 source   [90][88]
    float (*__restrict__ Fd)[88],        // u0 source -> dest  [90][88]
    const float* __restrict__ CD, const float* __restrict__ CG,  // 82x82
    const float* __restrict__ eff,
    int y0g, int x0g, float ds, int t)
{
    constexpr int NB = (N + 3) / 4;       // 4-row bands
    for (int slot = t; slot < NB * N; slot += 512) {
        const int band = slot / N;        // compile-time N -> magic mul
        const int x    = slot - band * N;
        const int lx   = OFF + x;
        const int yb   = OFF + band * 4;

        float a[4] = {0.f, 0.f, 0.f, 0.f};
        float c[4];
        // 10 rows shared by the 4 vertically-adjacent outputs: 70 reads / 4 px.
        // Lanes are consecutive in x -> conflict-free LDS.
        #pragma unroll
        for (int ky = 0; ky < 10; ++ky) {
            const int yy = yb + ky - 3;   // <= 89: pad rows absorb overreach
            float v[7];
            #pragma unroll
            for (int kx = 0; kx < 7; ++kx) v[kx] = Fs[yy][lx - 3 + kx];
            if (ky == 3) c[0] = v[3];
            if (ky == 4) c[1] = v[3];
            if (ky == 5) c[2] = v[3];
            if (ky == 6) c[3] = v[3];
            #pragma unroll
            for (int o = 0; o < 4; ++o) {
                const int kh = ky - o;
                if (kh >= 0 && kh < 7) {
                    #pragma unroll
                    for (int kx = 0; kx < 7; ++kx)
                        a[o] = fmaf(v[kx], eff[kh * 7 + kx], a[o]);
                }
            }
        }
        #pragma unroll
        for (int k = 0; k < 4; ++k) {
            if (band * 4 + k < N) {       // partial last band guard
                const int ly = yb + k;
                const int ci = (ly - 3) * 82 + (lx - 3);
                const float D1 = CD[ci];
                const float G  = CG[ci];
                const float u1 = c[k];
                const float u0 = Fd[ly][lx];
                float val = fmaf(D1, a[k], fmaf(G, u1 - u0, u1));
                if (y0g + ly == 128 && x0g + lx == 128)
                    val = fmaf(-D1, ds, val);     // source injection
                Fd[ly][lx] = val;
            }
        }
    }
}

// 4 FDTD steps per launch. Grid: (4,4,16) = 256 blocks = 1/CU. 512 threads.
__global__ __launch_bounds__(512, 2) void fdtd4(
    const float* __restrict__ U1,   const float* __restrict__ U0,
    const float* __restrict__ epsr, const float* __restrict__ sigma,
    const float* __restrict__ eff,  const float* __restrict__ src,
    float* __restrict__ NU1, float* __restrict__ NU0, int sbase)
{
    __shared__ float F[2][90][88];        // 2 field buffers (+2 pad rows each)
    __shared__ float CD[82 * 82];         // 1/(4e+sg)
    __shared__ float CG[82 * 82];         // (4e-sg)/(4e+sg)

    const int t   = threadIdx.x;
    const int x0g = blockIdx.x * 64 - 12;  // global coords of LDS (0,0)
    const int y0g = blockIdx.y * 64 - 12;
    const size_t bo = (size_t)blockIdx.z * DIM * DIM;

    // per-substep source amplitudes (uniform scalar loads)
    float dsr[4];
    #pragma unroll
    for (int r = 0; r < 4; ++r)
        dsr[r] = src[2 * (sbase + r)] - src[2 * (sbase + r) + 1];

    // ---- stage: F[0] <- u_s on [0,88)^2 ----
    for (int i = t; i < 88 * 88; i += 512) {
        const int y = i / 88, x = i - y * 88;
        const int gy = y0g + y, gx = x0g + x;
        float v = 0.f;
        if (gy >= 0 && gy < DIM && gx >= 0 && gx < DIM)
            v = U1[bo + (size_t)gy * DIM + gx];
        F[0][y][x] = v;
    }
    // ---- stage: F[1] <- u_{s-1} on [3,85)^2 ----
    for (int i = t; i < 82 * 82; i += 512) {
        const int y = i / 82, x = i - y * 82;
        const int ly = 3 + y, lx = 3 + x;
        const int gy = y0g + ly, gx = x0g + lx;
        float v = 0.f;
        if (gy >= 0 && gy < DIM && gx >= 0 && gx < DIM)
            v = U0[bo + (size_t)gy * DIM + gx];
        F[1][ly][lx] = v;
    }
    // ---- stage: coefficients on [3,85)^2 (0 outside image => OOB pixels stay 0) ----
    for (int i = t; i < 82 * 82; i += 512) {
        const int y = i / 82, x = i - y * 82;
        const int gy = y0g + 3 + y, gx = x0g + 3 + x;
        float d1 = 0.f, g = 0.f;
        if (gy >= 0 && gy < DIM && gx >= 0 && gx < DIM) {
            const size_t idx = bo + (size_t)gy * DIM + gx;
            const float e = epsr[idx], sg = sigma[idx];
            d1 = 1.f / (4.f * e + sg);
            g  = (4.f * e - sg) * d1;
        }
        CD[i] = d1;
        CG[i] = g;
    }
    __syncthreads();

    // ---- 4 fused steps, ping-ponging the two LDS field buffers ----
    substep<82, 3>(F[0], F[1], CD, CG, eff, y0g, x0g, dsr[0], t);  // u_{s+1} -> F1
    __syncthreads();
    substep<76, 6>(F[1], F[0], CD, CG, eff, y0g, x0g, dsr[1], t);  // u_{s+2} -> F0
    __syncthreads();
    substep<70, 9>(F[0], F[1], CD, CG, eff, y0g, x0g, dsr[2], t);  // u_{s+3} -> F1
    __syncthreads();
    substep<64, 12>(F[1], F[0], CD, CG, eff, y0g, x0g, dsr[3], t); // u_{s+4} -> F0
    __syncthreads();

    // ---- store interiors: NU1 = u_{s+4} (F0), NU0 = u_{s+3} (F1) ----
    for (int i = t; i < 64 * 64; i += 512) {
        const int iy = i >> 6, ix = i & 63;
        const int ly = 12 + iy, lx = 12 + ix;
        const size_t g = bo + (size_t)(y0g + ly) * DIM + (x0g + lx);
        NU1[g] = F[0][ly][lx];
        NU0[g] = F[1][ly][lx];
    }
}

extern "C" void kernel_launch(void* const* d_in, const int* in_sizes, int n_in,
                              void* d_out, int out_size, void* d_ws, size_t ws_size,
                              hipStream_t stream) {
    (void)in_sizes; (void)n_in; (void)out_size; (void)ws_size;

    const float* u1    = (const float*)d_in[0];
    const float* u0    = (const float*)d_in[1];
    const float* epsr  = (const float*)d_in[2];
    const float* sigma = (const float*)d_in[3];
    const float* fdk   = (const float*)d_in[4];
    const float* cw    = (const float*)d_in[5];
    const float* src   = (const float*)d_in[6];

    float* eff = (float*)d_ws;                          // 49 floats
    float* wsA = (float*)((char*)d_ws + 256);           // field buffers, 4 MB each
    float* wsB = wsA + (size_t)BATCH * DIM * DIM;
    float* wsC = wsB + (size_t)BATCH * DIM * DIM;
    float* out = (float*)d_out;

    prep_eff<<<1, 64, 0, stream>>>(fdk, cw, eff);

    dim3 grid(4, 4, BATCH);          // 256 blocks = 1 per CU
    const float* U1 = u1;
    const float* U0 = u0;
    for (int j = 0; j < 8; ++j) {    // 8 x 4 fused steps = 32
        float* NU1 = (j & 1) ? out : wsA;   // j=7 (odd) lands u_32 in d_out
        float* NU0 = (j & 1) ? wsC : wsB;
        fdtd4<<<grid, 512, 0, stream>>>(U1, U0, epsr, sigma, eff, src,
                                        NU1, NU0, 4 * j);
        U1 = NU1;
        U0 = NU0;
    }
}

// Round 5
// 315.758 us; speedup vs baseline: 6.6092x; 1.0319x over previous
//
#include <hip/hip_runtime.h>

#define DIM   256
#define BATCH 16
#define STEPS 32

// Fused-4 geometry: TS=64 output tile, halo 12, LDS region 88x88.
// Sub-step r (r=0..3) computes u_{s+r+1} on region [OFF, OFF+N) with
// OFF = 3*(r+1), N = 88 - 6*(r+1):  (82,3) (76,6) (70,9) (64,12).

// Collapse the 14 used fd_kernels into one effective 7x7 kernel.
// eff[t] = sum_{c=1..14} fdk[c,0,t] * cw[c-1]   (kernel 0 unused: u1fd[:,1:])
__global__ void prep_eff(const float* __restrict__ fdk,
                         const float* __restrict__ cw,
                         float* __restrict__ eff) {
    int t = threadIdx.x;
    if (t < 49) {
        float s = 0.f;
        #pragma unroll
        for (int c = 1; c < 15; ++c)
            s += fdk[c * 49 + t] * cw[c - 1];
        eff[t] = s;
    }
}

// One fused sub-step over LDS, 4 rows x 2 cols per thread (<=1 slot/thread).
//   out = D1*conv7x7(Fs) + u1 + G*(u1 - u0)
// Result overwrites Fd in place (single owner per pixel).
// OOB pixels stay exactly 0 (D1=G=0 and fields 0 outside the image).
template<int N, int OFF>
__device__ __forceinline__ void substep(
    const float (*__restrict__ Fs)[88],
    float (*__restrict__ Fd)[88],
    const float* __restrict__ CD, const float* __restrict__ CG,  // 82x82
    const float* __restrict__ eff,
    int y0g, int x0g, float ds, int t)
{
    constexpr int NCP   = N / 2;          // col-pairs (N always even)
    constexpr int NB    = (N + 3) / 4;    // 4-row bands
    constexpr int SLOTS = NB * NCP;
    static_assert(SLOTS <= 1024, "one slot per thread");

    if (t < SLOTS) {
        const int band = t / NCP;         // compile-time divisor
        const int cp   = t - band * NCP;
        const int lx   = OFF + 2 * cp;    // first of 2 owned cols
        const int yb   = OFF + 4 * band;  // first of 4 owned rows
        const int lxm3 = lx - 3;

        float a[4][2] = {{0.f,0.f},{0.f,0.f},{0.f,0.f},{0.f,0.f}};
        float c[4][2];
        // 10 rows x 8 cols shared by the 4x2 outputs: 80 LDS reads / 8 px.
        // Lanes stride-2 floats -> 2-way bank alias -> free.
        #pragma unroll
        for (int ky = 0; ky < 10; ++ky) {
            const int yy = yb + ky - 3;   // <= 89: pad rows absorb overreach
            float v[8];
            #pragma unroll
            for (int kx = 0; kx < 8; ++kx) v[kx] = Fs[yy][lxm3 + kx];
            if (ky >= 3 && ky <= 6) { c[ky - 3][0] = v[3]; c[ky - 3][1] = v[4]; }
            #pragma unroll
            for (int o = 0; o < 4; ++o) {
                const int kh = ky - o;
                if (kh >= 0 && kh < 7) {
                    #pragma unroll
                    for (int kx = 0; kx < 7; ++kx) {
                        const float E = eff[kh * 7 + kx];   // SGPR (uniform)
                        a[o][0] = fmaf(v[kx],     E, a[o][0]);
                        a[o][1] = fmaf(v[kx + 1], E, a[o][1]);
                    }
                }
            }
        }
        #pragma unroll
        for (int k = 0; k < 4; ++k) {
            if (4 * band + k < N) {       // partial last band guard
                const int ly = yb + k;
                #pragma unroll
                for (int cc = 0; cc < 2; ++cc) {
                    const int ci = (ly - 3) * 82 + (lxm3 + cc);
                    const float D1 = CD[ci];
                    const float G  = CG[ci];
                    const float u1 = c[k][cc];
                    const float u0 = Fd[ly][lx + cc];
                    float val = fmaf(D1, a[k][cc], fmaf(G, u1 - u0, u1));
                    if (y0g + ly == 128 && x0g + lx + cc == 128)
                        val = fmaf(-D1, ds, val);   // source injection
                    Fd[ly][lx + cc] = val;
                }
            }
        }
    }
}

// 4 FDTD steps per launch. Grid: (4,4,16) = 256 blocks = 1/CU.
// 1024 threads = 16 waves = 4/SIMD for latency hiding (round-4 had only 2).
__global__ __launch_bounds__(1024, 4) void fdtd4(
    const float* __restrict__ U1,   const float* __restrict__ U0,
    const float* __restrict__ epsr, const float* __restrict__ sigma,
    const float* __restrict__ eff,  const float* __restrict__ src,
    float* __restrict__ NU1, float* __restrict__ NU0, int sbase)
{
    __shared__ float F[2][90][88];        // 2 field buffers (+2 pad rows)
    __shared__ float CD[82 * 82];         // 1/(4e+sg)
    __shared__ float CG[82 * 82];         // (4e-sg)/(4e+sg)

    const int t   = threadIdx.x;
    const int x0g = blockIdx.x * 64 - 12; // global coords of LDS (0,0)
    const int y0g = blockIdx.y * 64 - 12;
    const size_t bo = (size_t)blockIdx.z * DIM * DIM;

    float dsr[4];
    #pragma unroll
    for (int r = 0; r < 4; ++r)
        dsr[r] = src[2 * (sbase + r)] - src[2 * (sbase + r) + 1];

    // ---- stage: F[0] <- u_s on [0,88)^2 ----
    for (int i = t; i < 88 * 88; i += 1024) {
        const int y = i / 88, x = i - y * 88;
        const int gy = y0g + y, gx = x0g + x;
        float v = 0.f;
        if (gy >= 0 && gy < DIM && gx >= 0 && gx < DIM)
            v = U1[bo + (size_t)gy * DIM + gx];
        F[0][y][x] = v;
    }
    // ---- stage: F[1] <- u_{s-1} on [3,85)^2 ----
    for (int i = t; i < 82 * 82; i += 1024) {
        const int y = i / 82, x = i - y * 82;
        const int ly = 3 + y, lx = 3 + x;
        const int gy = y0g + ly, gx = x0g + lx;
        float v = 0.f;
        if (gy >= 0 && gy < DIM && gx >= 0 && gx < DIM)
            v = U0[bo + (size_t)gy * DIM + gx];
        F[1][ly][lx] = v;
    }
    // ---- stage: coefficients on [3,85)^2 (0 outside image) ----
    for (int i = t; i < 82 * 82; i += 1024) {
        const int y = i / 82, x = i - y * 82;
        const int gy = y0g + 3 + y, gx = x0g + 3 + x;
        float d1 = 0.f, g = 0.f;
        if (gy >= 0 && gy < DIM && gx >= 0 && gx < DIM) {
            const size_t idx = bo + (size_t)gy * DIM + gx;
            const float e = epsr[idx], sg = sigma[idx];
            d1 = 1.f / (4.f * e + sg);
            g  = (4.f * e - sg) * d1;
        }
        CD[i] = d1;
        CG[i] = g;
    }
    __syncthreads();

    // ---- 4 fused steps, ping-ponging the two LDS field buffers ----
    substep<82, 3>(F[0], F[1], CD, CG, eff, y0g, x0g, dsr[0], t);  // u_{s+1} -> F1
    __syncthreads();
    substep<76, 6>(F[1], F[0], CD, CG, eff, y0g, x0g, dsr[1], t);  // u_{s+2} -> F0
    __syncthreads();
    substep<70, 9>(F[0], F[1], CD, CG, eff, y0g, x0g, dsr[2], t);  // u_{s+3} -> F1
    __syncthreads();
    substep<64, 12>(F[1], F[0], CD, CG, eff, y0g, x0g, dsr[3], t); // u_{s+4} -> F0
    __syncthreads();

    // ---- store interiors: NU1 = u_{s+4} (F0), NU0 = u_{s+3} (F1) ----
    for (int i = t; i < 64 * 64; i += 1024) {
        const int iy = i >> 6, ix = i & 63;
        const int ly = 12 + iy, lx = 12 + ix;
        const size_t g = bo + (size_t)(y0g + ly) * DIM + (x0g + lx);
        NU1[g] = F[0][ly][lx];
        NU0[g] = F[1][ly][lx];
    }
}

extern "C" void kernel_launch(void* const* d_in, const int* in_sizes, int n_in,
                              void* d_out, int out_size, void* d_ws, size_t ws_size,
                              hipStream_t stream) {
    (void)in_sizes; (void)n_in; (void)out_size; (void)ws_size;

    const float* u1    = (const float*)d_in[0];
    const float* u0    = (const float*)d_in[1];
    const float* epsr  = (const float*)d_in[2];
    const float* sigma = (const float*)d_in[3];
    const float* fdk   = (const float*)d_in[4];
    const float* cw    = (const float*)d_in[5];
    const float* src   = (const float*)d_in[6];

    float* eff = (float*)d_ws;                          // 49 floats
    float* wsA = (float*)((char*)d_ws + 256);           // field buffers, 4 MB each
    float* wsB = wsA + (size_t)BATCH * DIM * DIM;
    float* wsC = wsB + (size_t)BATCH * DIM * DIM;
    float* out = (float*)d_out;

    prep_eff<<<1, 64, 0, stream>>>(fdk, cw, eff);

    dim3 grid(4, 4, BATCH);          // 256 blocks = 1 per CU
    const float* U1 = u1;
    const float* U0 = u0;
    for (int j = 0; j < 8; ++j) {    // 8 x 4 fused steps = 32
        float* NU1 = (j & 1) ? out : wsA;   // j=7 (odd) lands u_32 in d_out
        float* NU0 = (j & 1) ? wsC : wsB;
        fdtd4<<<grid, 1024, 0, stream>>>(U1, U0, epsr, sigma, eff, src,
                                         NU1, NU0, 4 * j);
        U1 = NU1;
        U0 = NU0;
    }
}